// Round 5
// baseline (670.478 us; speedup 1.0000x reference)
//
#include <hip/hip_runtime.h>
#include <hip/hip_cooperative_groups.h>
#include <math.h>
#include <limits.h>

namespace cg = cooperative_groups;

#define BB 4
#define SS 2048
#define HH 768
#define MAXSEG 256
#define NUM_POS (BB*(SS/4))   // 2048
#define NEG_BIG -1000000000.0f

typedef _Float16 f16x8 __attribute__((ext_vector_type(8)));
typedef _Float16 f16x4 __attribute__((ext_vector_type(4)));
typedef float    f32x4 __attribute__((ext_vector_type(4)));

// Single cooperative kernel: all phases separated by grid.sync().
// 1024 blocks x 256 threads = 4 blocks/CU (16 waves/CU) — co-resident by
// construction (LDS ~10.3 KB/block, VGPR capped at 128 via launch_bounds).
// NOTE: no early returns anywhere — every block reaches every grid.sync().
__global__ __launch_bounds__(256, 4) void k_fused(
    const float* __restrict__ es, const float* __restrict__ W,
    const float* __restrict__ bias, const int* __restrict__ ind,
    const int* __restrict__ clc,
    int* __restrict__ seg_id, int* __restrict__ seg_start,
    int* __restrict__ nseg, int* __restrict__ pos_local, int* __restrict__ pos_cnt,
    int* __restrict__ allowCnt, int* __restrict__ firstAllow,
    float* __restrict__ lse, int* __restrict__ amax,
    _Float16* __restrict__ segsum_h, _Float16* __restrict__ Wh,
    _Float16* __restrict__ Uh, float* __restrict__ G, float* __restrict__ out)
{
  cg::grid_group grid = cg::this_grid();
  int t = threadIdx.x;
  int lane = t & 63, wid = t >> 6;

  __shared__ int sInd[SS];
  __shared__ int sWave[4];
  __shared__ int sAC[MAXSEG];
  __shared__ int sFA[MAXSEG];
  __shared__ int sBase[BB+1];
  __shared__ float sL0[4], sC0[4], sL1[4], sC1[4];

  // ---------------- Phase 0: scan (blocks 0..3) || W cast (blocks 4..579) ---
  if (blockIdx.x < BB) {
    int b = blockIdx.x;
    for (int i = t; i < SS; i += 256) sInd[i] = ind[b*SS + i];
    sAC[t] = 0; sFA[t] = INT_MAX;
    __syncthreads();

    int i0 = t * 8;
    int f[8], cv[8];
    int lsum = 0;
    #pragma unroll
    for (int u = 0; u < 8; u++) {
      int i = i0 + u;
      f[u] = (i == 0) ? 0 : (sInd[i] != sInd[i-1]);
      cv[u] = clc[b*SS + i];
      lsum += f[u];
    }
    int x = lsum;
    #pragma unroll
    for (int off = 1; off < 64; off <<= 1) {
      int v = __shfl_up(x, off, 64);
      if (lane >= off) x += v;
    }
    if (lane == 63) sWave[wid] = x;
    __syncthreads();
    int base = 0;
    for (int w = 0; w < wid; w++) base += sWave[w];
    int run = base + x - lsum;
    int rid[8];
    #pragma unroll
    for (int u = 0; u < 8; u++) {
      int i = i0 + u;
      run += f[u];
      rid[u] = run;
      seg_id[b*SS + i] = run;
      if (f[u] || i == 0) seg_start[b*(MAXSEG+1) + run] = i;
    }
    if (t == 255) { nseg[b] = run + 1; seg_start[b*(MAXSEG+1) + run + 1] = SS; }

    #pragma unroll
    for (int u = 0; u < 8; u++) {
      if (cv[u] < 0) {
        atomicAdd(&sAC[rid[u]], 1);
        atomicMin(&sFA[rid[u]], i0 + u);
      }
    }
    __syncthreads();
    allowCnt[b*MAXSEG + t]   = sAC[t];
    firstAllow[b*MAXSEG + t] = sFA[t];

    int psum = 0;
    int p[8];
    #pragma unroll
    for (int u = 0; u < 8; u++) { p[u] = (cv[u] > 0) ? 1 : 0; psum += p[u]; }
    x = psum;
    #pragma unroll
    for (int off = 1; off < 64; off <<= 1) {
      int v = __shfl_up(x, off, 64);
      if (lane >= off) x += v;
    }
    __syncthreads();
    if (lane == 63) sWave[wid] = x;
    __syncthreads();
    base = 0;
    for (int w = 0; w < wid; w++) base += sWave[w];
    int rank = base + x - psum;
    #pragma unroll
    for (int u = 0; u < 8; u++) {
      if (p[u]) { pos_local[b*SS + rank] = i0 + u; rank++; }
    }
    if (t == 255) pos_cnt[b] = rank;
  } else if (blockIdx.x < BB + 576) {
    int idx = (blockIdx.x - BB)*256 + t;     // float4 index; 147456 total
    float4 v = ((const float4*)W)[idx];
    f16x4 h;
    h[0] = (_Float16)v.x; h[1] = (_Float16)v.y;
    h[2] = (_Float16)v.z; h[3] = (_Float16)v.w;
    *(f16x4*)(Wh + (size_t)idx*4) = h;
  }
  grid.sync();

  // ---------------- Phase 1: segment sums (1024 blocks, float4 lanes) -------
  {
    int blk = blockIdx.x;           // exactly BB*MAXSEG = 1024 blocks
    int b = blk >> 8, s = blk & 255;
    if (t < 192) {
      float4 acc = {0.f, 0.f, 0.f, 0.f};
      if (s < nseg[b]) {
        int st = seg_start[b*(MAXSEG+1) + s];
        int en = seg_start[b*(MAXSEG+1) + s + 1];
        const float* basep = es + (size_t)b*SS*HH + t*4;
        for (int i = st; i < en; i++) {
          float4 v = *(const float4*)(basep + (size_t)i*HH);
          acc.x += v.x; acc.y += v.y; acc.z += v.z; acc.w += v.w;
        }
      }
      f16x4 h;
      h[0] = (_Float16)acc.x; h[1] = (_Float16)acc.y;
      h[2] = (_Float16)acc.z; h[3] = (_Float16)acc.w;
      *(f16x4*)(segsum_h + ((size_t)b*MAXSEG + s)*HH + t*4) = h;
    }
  }
  grid.sync();

  // ---------------- Phase 2: U = tanh(segsum @ W^T + bias), MFMA f16 --------
  // 768 wave-tiles (32x32 each) over 1024x768; blocks 0..191, 4 waves each.
  if (blockIdx.x < 192) {
    int tile = blockIdx.x*4 + wid;        // 0..767 over 32 x 24 tiles
    int tm = tile / 24, tn = tile % 24;
    int rb = tm*32, cb = tn*32;
    int m0 = lane & 15, quad = lane >> 4;
    const _Float16* A0 = segsum_h + (size_t)(rb + m0)*HH + quad*8;
    const _Float16* A1 = A0 + (size_t)16*HH;
    const _Float16* B0 = Wh + (size_t)(cb + m0)*HH + quad*8;
    const _Float16* B1 = B0 + (size_t)16*HH;
    f32x4 acc00 = {0.f,0.f,0.f,0.f}, acc01 = {0.f,0.f,0.f,0.f};
    f32x4 acc10 = {0.f,0.f,0.f,0.f}, acc11 = {0.f,0.f,0.f,0.f};
    #pragma unroll 4
    for (int k0 = 0; k0 < HH; k0 += 32) {
      f16x8 a0 = *(const f16x8*)(A0 + k0);
      f16x8 a1 = *(const f16x8*)(A1 + k0);
      f16x8 b0 = *(const f16x8*)(B0 + k0);
      f16x8 b1 = *(const f16x8*)(B1 + k0);
      acc00 = __builtin_amdgcn_mfma_f32_16x16x32_f16(a0, b0, acc00, 0, 0, 0);
      acc01 = __builtin_amdgcn_mfma_f32_16x16x32_f16(a0, b1, acc01, 0, 0, 0);
      acc10 = __builtin_amdgcn_mfma_f32_16x16x32_f16(a1, b0, acc10, 0, 0, 0);
      acc11 = __builtin_amdgcn_mfma_f32_16x16x32_f16(a1, b1, acc11, 0, 0, 0);
    }
    float bc0 = bias[cb + m0], bc1 = bias[cb + 16 + m0];
    int r0 = rb + quad*4;
    #pragma unroll
    for (int i = 0; i < 4; i++) {
      Uh[(size_t)(r0+i)*HH    + cb + m0]      = (_Float16)tanhf(acc00[i] + bc0);
      Uh[(size_t)(r0+i)*HH    + cb + 16 + m0] = (_Float16)tanhf(acc01[i] + bc1);
      Uh[(size_t)(r0+16+i)*HH + cb + m0]      = (_Float16)tanhf(acc10[i] + bc0);
      Uh[(size_t)(r0+16+i)*HH + cb + 16 + m0] = (_Float16)tanhf(acc11[i] + bc1);
    }
  }
  grid.sync();

  // ---------------- Phase 3: Gram G[b] = U[b] U[b]^T, MFMA f16 --------------
  // 1024 wave-tiles (16x16) over 4 batches; blocks 0..255.
  if (blockIdx.x < 256) {
    int tile = blockIdx.x*4 + wid;        // 0..1023
    int b = tile >> 8, rem = tile & 255;
    int rb = (rem >> 4)*16, cb = (rem & 15)*16;
    int m0 = lane & 15, quad = lane >> 4;
    const _Float16* Ub = Uh + (size_t)b*MAXSEG*HH;
    const _Float16* A0 = Ub + (size_t)(rb + m0)*HH + quad*8;
    const _Float16* B0 = Ub + (size_t)(cb + m0)*HH + quad*8;
    f32x4 acc = {0.f,0.f,0.f,0.f};
    #pragma unroll 4
    for (int k0 = 0; k0 < HH; k0 += 32) {
      f16x8 a  = *(const f16x8*)(A0 + k0);
      f16x8 bb = *(const f16x8*)(B0 + k0);
      acc = __builtin_amdgcn_mfma_f32_16x16x32_f16(a, bb, acc, 0, 0, 0);
    }
    float* Gb = G + (size_t)b*MAXSEG*MAXSEG;
    int r0 = rb + quad*4;
    #pragma unroll
    for (int i = 0; i < 4; i++)
      Gb[(size_t)(r0+i)*MAXSEG + cb + m0] = acc[i];
  }
  grid.sync();

  // ---------------- Phase 4: per-(b,seg) logsumexp + argmax -----------------
  if (blockIdx.x < 256) {
    int row = blockIdx.x * 4 + wid;
    int b = row >> 8, si = row & 255;
    if (si < nseg[b]) {
      const float* g = G + ((size_t)b*MAXSEG + si)*MAXSEG;
      const int* ac = allowCnt + b*MAXSEG;
      const int* fa = firstAllow + b*MAXSEG;
      float gv[4]; int av[4], fv[4];
      #pragma unroll
      for (int q = 0; q < 4; q++) {
        int s = lane + 64*q;
        gv[q] = g[s]; av[q] = ac[s]; fv[q] = fa[s];
      }
      float m = -INFINITY;
      #pragma unroll
      for (int q = 0; q < 4; q++) if (av[q] > 0) m = fmaxf(m, gv[q]);
      #pragma unroll
      for (int off = 32; off > 0; off >>= 1) m = fmaxf(m, __shfl_xor(m, off, 64));
      float s = 0.f;
      #pragma unroll
      for (int q = 0; q < 4; q++) if (av[q] > 0) s += (float)av[q] * expf(gv[q] - m);
      #pragma unroll
      for (int off = 32; off > 0; off >>= 1) s += __shfl_xor(s, off, 64);
      float bv = -INFINITY; int bi = INT_MAX;
      #pragma unroll
      for (int q = 0; q < 4; q++) {
        if (av[q] > 0 && (gv[q] > bv || (gv[q] == bv && fv[q] < bi))) { bv = gv[q]; bi = fv[q]; }
      }
      #pragma unroll
      for (int off = 32; off > 0; off >>= 1) {
        float ov = __shfl_xor(bv, off, 64);
        int   oi = __shfl_xor(bi, off, 64);
        if (ov > bv || (ov == bv && oi < bi)) { bv = ov; bi = oi; }
      }
      if (lane == 0) {
        lse[row]  = m + logf(s);
        amax[row] = bi;
      }
    }
  }
  grid.sync();

  // ---------------- Phase 5: positives -> 6 output scalars (block 0) --------
  if (blockIdx.x == 0) {
    if (t == 0) {
      int acc = 0; sBase[0] = 0;
      for (int b = 0; b < BB; b++) { acc += pos_cnt[b]; sBase[b+1] = acc; }
    }
    __syncthreads();
    int total = sBase[BB];
    if (total > NUM_POS) total = NUM_POS;
    float l0 = 0.f, c0 = 0.f, l1 = 0.f, c1 = 0.f;
    for (int r = t; r < total; r += 256) {
      int b = 0;
      while (b < BB-1 && r >= sBase[b+1]) b++;
      int k = r - sBase[b];
      int i  = pos_local[b*SS + k];
      int si = seg_id[b*SS + i];
      int L  = clc[b*SS + i];
      int sL = seg_id[b*SS + L];
      float vL = G[((size_t)b*MAXSEG + si)*MAXSEG + sL] + (clc[b*SS + L] < 0 ? 0.0f : NEG_BIG);
      float loss = lse[b*MAXSEG + si] - vL;
      float corr = (amax[b*MAXSEG + si] == L) ? 1.0f : 0.0f;
      if (r & 1) { l1 += loss; c1 += corr; } else { l0 += loss; c0 += corr; }
    }
    #pragma unroll
    for (int off = 32; off > 0; off >>= 1) {
      l0 += __shfl_down(l0, off, 64);
      c0 += __shfl_down(c0, off, 64);
      l1 += __shfl_down(l1, off, 64);
      c1 += __shfl_down(c1, off, 64);
    }
    if (lane == 0) { sL0[wid] = l0; sC0[wid] = c0; sL1[wid] = l1; sC1[wid] = c1; }
    __syncthreads();
    if (t == 0) {
      float L0 = sL0[0]+sL0[1]+sL0[2]+sL0[3];
      float C0 = sC0[0]+sC0[1]+sC0[2]+sC0[3];
      float L1 = sL1[0]+sL1[1]+sL1[2]+sL1[3];
      float C1 = sC1[0]+sC1[1]+sC1[2]+sC1[3];
      float n = (float)(NUM_POS/2);   // 1024
      out[0] = L0 / n;
      out[1] = C0;
      out[2] = n + 1e-6f;
      out[3] = L1 / n;
      out[4] = C1;
      out[5] = n + 1e-6f;
    }
  }
}

// ---------------------------------------------------------------------------
extern "C" void kernel_launch(void* const* d_in, const int* in_sizes, int n_in,
                              void* d_out, int out_size, void* d_ws, size_t ws_size,
                              hipStream_t stream)
{
  const float* es   = (const float*)d_in[0];
  const float* W    = (const float*)d_in[1];
  const float* bias = (const float*)d_in[2];
  const int*   ind  = (const int*)d_in[3];
  const int*   clc  = (const int*)d_in[4];
  float* out = (float*)d_out;

  char* ws = (char*)d_ws;
  int*   nseg       = (int*)(ws + 0);
  int*   pos_cnt    = (int*)(ws + 256);
  int*   seg_start  = (int*)(ws + 1024);                 // B*(MAXSEG+1)
  int*   seg_id     = (int*)(ws + 8192);                 // B*S
  int*   pos_local  = (int*)(ws + 40960);                // B*S
  int*   allowCnt   = (int*)(ws + 73728);                // B*256
  int*   firstAllow = (int*)(ws + 77824);
  float* lse        = (float*)(ws + 81920);
  int*   amax       = (int*)(ws + 86016);
  _Float16* segsum_h = (_Float16*)(ws + 90112);          // 1.5 MB
  _Float16* Wh       = (_Float16*)(ws + 1662976);        // 1.125 MB
  _Float16* Uh       = (_Float16*)(ws + 2842624);        // 1.5 MB
  float*    G        = (float*)(ws + 4415488);           // 1 MB

  void* args[] = { (void*)&es, (void*)&W, (void*)&bias, (void*)&ind, (void*)&clc,
                   (void*)&seg_id, (void*)&seg_start, (void*)&nseg,
                   (void*)&pos_local, (void*)&pos_cnt,
                   (void*)&allowCnt, (void*)&firstAllow,
                   (void*)&lse, (void*)&amax,
                   (void*)&segsum_h, (void*)&Wh, (void*)&Uh,
                   (void*)&G, (void*)&out };
  hipLaunchCooperativeKernel((void*)k_fused, dim3(1024), dim3(256), args, 0, stream);
}

// Round 6
// 132.434 us; speedup vs baseline: 5.0627x; 5.0627x over previous
//
#include <hip/hip_runtime.h>
#include <math.h>
#include <limits.h>

#define BB 4
#define SS 2048
#define HH 768
#define MAXSEG 256
#define NUM_POS (BB*(SS/4))   // 2048
#define NEG_BIG -1000000000.0f

typedef _Float16 f16x8 __attribute__((ext_vector_type(8)));
typedef _Float16 f16x4 __attribute__((ext_vector_type(4)));
typedef float    f32x4 __attribute__((ext_vector_type(4)));

// 256-thread exclusive scan (4 waves, shfl + LDS). Caller must __syncthreads()
// between consecutive uses (sWave reuse).
__device__ __forceinline__ int blockExclScan(int v, int* sWave, int lane, int wid)
{
  int x = v;
  #pragma unroll
  for (int off = 1; off < 64; off <<= 1) {
    int y = __shfl_up(x, off, 64);
    if (lane >= off) x += y;
  }
  if (lane == 63) sWave[wid] = x;
  __syncthreads();
  int base = 0;
  for (int w = 0; w < wid; w++) base += sWave[w];
  return base + x - v;
}

// ---------------------------------------------------------------------------
// Kernel 1: blocks 0..3 = per-batch scan (+ positive bucketing by segment);
//           blocks 4..579 = W f32->f16 cast. Block 0 also zeroes accum/counter.
// ---------------------------------------------------------------------------
__global__ __launch_bounds__(256) void k_scan(
    const int* __restrict__ ind, const int* __restrict__ clc,
    const float* __restrict__ W, _Float16* __restrict__ Wh,
    int* __restrict__ seg_id, int* __restrict__ seg_start,
    int* __restrict__ nseg, int* __restrict__ pos_cnt,
    int* __restrict__ allowCnt, int* __restrict__ firstAllow,
    int* __restrict__ posSegOff, int* __restrict__ posSeg,
    float* __restrict__ accum, int* __restrict__ counter)
{
  int t = threadIdx.x;
  if (blockIdx.x >= BB) {
    int idx = (blockIdx.x - BB)*256 + t;     // float4 index; 147456 total
    float4 v = ((const float4*)W)[idx];
    f16x4 h;
    h[0] = (_Float16)v.x; h[1] = (_Float16)v.y;
    h[2] = (_Float16)v.z; h[3] = (_Float16)v.w;
    *(f16x4*)(Wh + (size_t)idx*4) = h;
    return;
  }
  int b = blockIdx.x;
  int lane = t & 63, wid = t >> 6;
  __shared__ int sInd[SS];
  __shared__ int sWave[4];
  __shared__ int sAC[MAXSEG];
  __shared__ int sFA[MAXSEG];
  if (b == 0 && t < 4) accum[t] = 0.f;
  if (b == 0 && t == 4) *counter = 0;
  for (int i = t; i < SS; i += 256) sInd[i] = ind[b*SS + i];
  sAC[t] = 0; sFA[t] = INT_MAX;
  __syncthreads();

  // --- segment boundaries ---
  int i0 = t * 8;
  int f[8], cv[8];
  int lsum = 0;
  #pragma unroll
  for (int u = 0; u < 8; u++) {
    int i = i0 + u;
    f[u] = (i == 0) ? 0 : (sInd[i] != sInd[i-1]);
    cv[u] = clc[b*SS + i];
    lsum += f[u];
  }
  int run = blockExclScan(lsum, sWave, lane, wid);
  int rid[8];
  #pragma unroll
  for (int u = 0; u < 8; u++) {
    int i = i0 + u;
    run += f[u];
    rid[u] = run;
    seg_id[b*SS + i] = run;
    if (f[u] || i == 0) seg_start[b*(MAXSEG+1) + run] = i;
  }
  if (t == 255) { nseg[b] = run + 1; seg_start[b*(MAXSEG+1) + run + 1] = SS; }

  // --- allowed-column stats ---
  #pragma unroll
  for (int u = 0; u < 8; u++) {
    if (cv[u] < 0) {
      atomicAdd(&sAC[rid[u]], 1);
      atomicMin(&sFA[rid[u]], i0 + u);
    }
  }
  __syncthreads();
  allowCnt[b*MAXSEG + t]   = sAC[t];
  firstAllow[b*MAXSEG + t] = sFA[t];
  __syncthreads();

  // --- positive ranks (local k within batch) ---
  int p[8], kk[8];
  int psum = 0;
  #pragma unroll
  for (int u = 0; u < 8; u++) { p[u] = (cv[u] > 0) ? 1 : 0; psum += p[u]; }
  int rank = blockExclScan(psum, sWave, lane, wid);
  #pragma unroll
  for (int u = 0; u < 8; u++) {
    kk[u] = rank;
    if (p[u]) rank++;
  }
  if (t == 255) pos_cnt[b] = rank;
  __syncthreads();

  // --- bucket positives by segment ---
  sAC[t] = 0;
  __syncthreads();
  #pragma unroll
  for (int u = 0; u < 8; u++) if (p[u]) atomicAdd(&sAC[rid[u]], 1);
  __syncthreads();
  int cnt = sAC[t];
  int off = blockExclScan(cnt, sWave, lane, wid);
  posSegOff[b*(MAXSEG+1) + t] = off;
  if (t == 255) posSegOff[b*(MAXSEG+1) + 256] = off + cnt;
  __syncthreads();
  sFA[t] = off;                 // scatter cursor
  __syncthreads();
  #pragma unroll
  for (int u = 0; u < 8; u++) {
    if (p[u]) {
      int pos = atomicAdd(&sFA[rid[u]], 1);
      posSeg[b*SS + pos] = (kk[u] << 16) | (i0 + u);
    }
  }
}

// ---------------------------------------------------------------------------
// Kernel 2: segment sums (f32 accumulate -> f16). 1024 blocks x 192 threads.
// ---------------------------------------------------------------------------
__global__ __launch_bounds__(192) void k_segsum(
    const float* __restrict__ es, const int* __restrict__ seg_start,
    const int* __restrict__ nseg, _Float16* __restrict__ segsum_h)
{
  int blk = blockIdx.x, t = threadIdx.x;
  int b = blk >> 8, s = blk & 255;
  float4 acc = {0.f, 0.f, 0.f, 0.f};
  if (s < nseg[b]) {
    int st = seg_start[b*(MAXSEG+1) + s];
    int en = seg_start[b*(MAXSEG+1) + s + 1];
    const float* basep = es + (size_t)b*SS*HH + t*4;
    for (int i = st; i < en; i++) {
      float4 v = *(const float4*)(basep + (size_t)i*HH);
      acc.x += v.x; acc.y += v.y; acc.z += v.z; acc.w += v.w;
    }
  }
  f16x4 h;
  h[0] = (_Float16)acc.x; h[1] = (_Float16)acc.y;
  h[2] = (_Float16)acc.z; h[3] = (_Float16)acc.w;
  *(f16x4*)(segsum_h + ((size_t)b*MAXSEG + s)*HH + t*4) = h;
}

// ---------------------------------------------------------------------------
// Kernel 3: U = tanh(segsum @ W^T + bias), f16 MFMA, direct-global fragments.
// Wave = 32x32 tile (2x2 of 16x16x32). 768 tiles -> 192 blocks.
// ---------------------------------------------------------------------------
__global__ __launch_bounds__(256) void k_gemmU(
    const _Float16* __restrict__ Ah, const _Float16* __restrict__ Wh,
    const float* __restrict__ bias, _Float16* __restrict__ Uh)
{
  int tid = threadIdx.x;
  int w = tid >> 6, lane = tid & 63;
  int tile = blockIdx.x*4 + w;          // 0..767 over 32 x 24 tiles
  int tm = tile / 24, tn = tile % 24;
  int rb = tm*32, cb = tn*32;
  int m0 = lane & 15, quad = lane >> 4;
  const _Float16* A0 = Ah + (size_t)(rb + m0)*HH + quad*8;
  const _Float16* A1 = A0 + (size_t)16*HH;
  const _Float16* B0 = Wh + (size_t)(cb + m0)*HH + quad*8;
  const _Float16* B1 = B0 + (size_t)16*HH;
  f32x4 acc00 = {0.f,0.f,0.f,0.f}, acc01 = {0.f,0.f,0.f,0.f};
  f32x4 acc10 = {0.f,0.f,0.f,0.f}, acc11 = {0.f,0.f,0.f,0.f};
  #pragma unroll 4
  for (int k0 = 0; k0 < HH; k0 += 32) {
    f16x8 a0 = *(const f16x8*)(A0 + k0);
    f16x8 a1 = *(const f16x8*)(A1 + k0);
    f16x8 b0 = *(const f16x8*)(B0 + k0);
    f16x8 b1 = *(const f16x8*)(B1 + k0);
    acc00 = __builtin_amdgcn_mfma_f32_16x16x32_f16(a0, b0, acc00, 0, 0, 0);
    acc01 = __builtin_amdgcn_mfma_f32_16x16x32_f16(a0, b1, acc01, 0, 0, 0);
    acc10 = __builtin_amdgcn_mfma_f32_16x16x32_f16(a1, b0, acc10, 0, 0, 0);
    acc11 = __builtin_amdgcn_mfma_f32_16x16x32_f16(a1, b1, acc11, 0, 0, 0);
  }
  float bc0 = bias[cb + m0], bc1 = bias[cb + 16 + m0];
  int r0 = rb + quad*4;
  #pragma unroll
  for (int i = 0; i < 4; i++) {
    Uh[(size_t)(r0+i)*HH    + cb + m0]      = (_Float16)tanhf(acc00[i] + bc0);
    Uh[(size_t)(r0+i)*HH    + cb + 16 + m0] = (_Float16)tanhf(acc01[i] + bc1);
    Uh[(size_t)(r0+16+i)*HH + cb + m0]      = (_Float16)tanhf(acc10[i] + bc0);
    Uh[(size_t)(r0+16+i)*HH + cb + 16 + m0] = (_Float16)tanhf(acc11[i] + bc1);
  }
}

// ---------------------------------------------------------------------------
// Kernel 4: Gram G[b] = U[b] U[b]^T, f16 MFMA. Wave = one 16x16 tile.
// ---------------------------------------------------------------------------
__global__ __launch_bounds__(256) void k_gram(
    const _Float16* __restrict__ Uh, float* __restrict__ G)
{
  int tid = threadIdx.x;
  int w = tid >> 6, lane = tid & 63;
  int tile = blockIdx.x*4 + w;          // 0..1023
  int b = tile >> 8, rem = tile & 255;
  int rb = (rem >> 4)*16, cb = (rem & 15)*16;
  int m0 = lane & 15, quad = lane >> 4;
  const _Float16* Ub = Uh + (size_t)b*MAXSEG*HH;
  const _Float16* A0 = Ub + (size_t)(rb + m0)*HH + quad*8;
  const _Float16* B0 = Ub + (size_t)(cb + m0)*HH + quad*8;
  f32x4 acc = {0.f,0.f,0.f,0.f};
  #pragma unroll 4
  for (int k0 = 0; k0 < HH; k0 += 32) {
    f16x8 a  = *(const f16x8*)(A0 + k0);
    f16x8 bb = *(const f16x8*)(B0 + k0);
    acc = __builtin_amdgcn_mfma_f32_16x16x32_f16(a, bb, acc, 0, 0, 0);
  }
  float* Gb = G + (size_t)b*MAXSEG*MAXSEG;
  int r0 = rb + quad*4;
  #pragma unroll
  for (int i = 0; i < 4; i++)
    Gb[(size_t)(r0+i)*MAXSEG + cb + m0] = acc[i];
}

// ---------------------------------------------------------------------------
// Kernel 5: per-(b,seg) wave: logsumexp + argmax + bucketed positive losses;
// block-level reduction -> 4 atomics; last block finalizes the 6 outputs.
// ---------------------------------------------------------------------------
__global__ __launch_bounds__(256) void k_tail(
    const float* __restrict__ G, const int* __restrict__ seg_id,
    const int* __restrict__ clc, const int* __restrict__ nseg,
    const int* __restrict__ pos_cnt, const int* __restrict__ allowCnt,
    const int* __restrict__ firstAllow, const int* __restrict__ posSegOff,
    const int* __restrict__ posSeg,
    float* __restrict__ accum, int* __restrict__ counter,
    float* __restrict__ out)
{
  __shared__ float sP[4][4];   // [wave][l0,c0,l1,c1]
  int t = threadIdx.x;
  int lane = t & 63, wid = t >> 6;
  int row = blockIdx.x * 4 + wid;
  int b = row >> 8, si = row & 255;

  float l0 = 0.f, c0 = 0.f, l1 = 0.f, c1 = 0.f;
  if (si < nseg[b]) {
    const float* g = G + ((size_t)b*MAXSEG + si)*MAXSEG;
    const int* ac = allowCnt + b*MAXSEG;
    const int* fa = firstAllow + b*MAXSEG;
    float gv[4]; int av[4], fv[4];
    #pragma unroll
    for (int q = 0; q < 4; q++) {
      int s = lane + 64*q;
      gv[q] = g[s]; av[q] = ac[s]; fv[q] = fa[s];
    }
    // max over allowed segments
    float m = -INFINITY;
    #pragma unroll
    for (int q = 0; q < 4; q++) if (av[q] > 0) m = fmaxf(m, gv[q]);
    #pragma unroll
    for (int off = 32; off > 0; off >>= 1) m = fmaxf(m, __shfl_xor(m, off, 64));
    // weighted exp-sum (masked cols underflow to exactly 0, as in reference)
    float s = 0.f;
    #pragma unroll
    for (int q = 0; q < 4; q++) if (av[q] > 0) s += (float)av[q] * expf(gv[q] - m);
    #pragma unroll
    for (int off = 32; off > 0; off >>= 1) s += __shfl_xor(s, off, 64);
    // first-occurrence argmax
    float bv = -INFINITY; int bi = INT_MAX;
    #pragma unroll
    for (int q = 0; q < 4; q++) {
      if (av[q] > 0 && (gv[q] > bv || (gv[q] == bv && fv[q] < bi))) { bv = gv[q]; bi = fv[q]; }
    }
    #pragma unroll
    for (int off = 32; off > 0; off >>= 1) {
      float ov = __shfl_xor(bv, off, 64);
      int   oi = __shfl_xor(bi, off, 64);
      if (ov > bv || (ov == bv && oi < bi)) { bv = ov; bi = oi; }
    }
    float lseV = m + logf(s);       // all lanes hold full value

    // positives belonging to this segment
    int base_b = 0;
    for (int bb2 = 0; bb2 < b; bb2++) base_b += pos_cnt[bb2];
    int st = posSegOff[b*(MAXSEG+1) + si];
    int en = posSegOff[b*(MAXSEG+1) + si + 1];
    for (int pp = st + lane; pp < en; pp += 64) {
      int e = posSeg[b*SS + pp];
      int i = e & 0xFFFF, k = e >> 16;
      int L = clc[b*SS + i];
      int sL = seg_id[b*SS + L];
      float vL = G[((size_t)b*MAXSEG + si)*MAXSEG + sL]
               + (clc[b*SS + L] < 0 ? 0.0f : NEG_BIG);
      float loss = lseV - vL;
      float corr = (bi == L) ? 1.0f : 0.0f;
      if ((base_b + k) & 1) { l1 += loss; c1 += corr; }
      else                  { l0 += loss; c0 += corr; }
    }
  }
  #pragma unroll
  for (int off = 32; off > 0; off >>= 1) {
    l0 += __shfl_down(l0, off, 64);
    c0 += __shfl_down(c0, off, 64);
    l1 += __shfl_down(l1, off, 64);
    c1 += __shfl_down(c1, off, 64);
  }
  if (lane == 0) { sP[wid][0] = l0; sP[wid][1] = c0; sP[wid][2] = l1; sP[wid][3] = c1; }
  __syncthreads();
  if (t == 0) {
    float v0 = sP[0][0]+sP[1][0]+sP[2][0]+sP[3][0];
    float v1 = sP[0][1]+sP[1][1]+sP[2][1]+sP[3][1];
    float v2 = sP[0][2]+sP[1][2]+sP[2][2]+sP[3][2];
    float v3 = sP[0][3]+sP[1][3]+sP[2][3]+sP[3][3];
    atomicAdd(&accum[0], v0);
    atomicAdd(&accum[1], v1);
    atomicAdd(&accum[2], v2);
    atomicAdd(&accum[3], v3);
    __threadfence();
    int old = atomicAdd(counter, 1);
    if (old == gridDim.x - 1) {       // last block finalizes
      float L0 = atomicAdd(&accum[0], 0.0f);
      float C0 = atomicAdd(&accum[1], 0.0f);
      float L1 = atomicAdd(&accum[2], 0.0f);
      float C1 = atomicAdd(&accum[3], 0.0f);
      float n = (float)(NUM_POS/2);   // 1024
      out[0] = L0 / n;
      out[1] = C0;
      out[2] = n + 1e-6f;
      out[3] = L1 / n;
      out[4] = C1;
      out[5] = n + 1e-6f;
    }
  }
}

// ---------------------------------------------------------------------------
extern "C" void kernel_launch(void* const* d_in, const int* in_sizes, int n_in,
                              void* d_out, int out_size, void* d_ws, size_t ws_size,
                              hipStream_t stream)
{
  const float* es   = (const float*)d_in[0];
  const float* W    = (const float*)d_in[1];
  const float* bias = (const float*)d_in[2];
  const int*   ind  = (const int*)d_in[3];
  const int*   clc  = (const int*)d_in[4];
  float* out = (float*)d_out;

  char* ws = (char*)d_ws;
  float* accum      = (float*)(ws + 0);                  // 4 floats
  int*   counter    = (int*)(ws + 16);
  int*   nseg       = (int*)(ws + 256);
  int*   pos_cnt    = (int*)(ws + 512);
  int*   seg_start  = (int*)(ws + 1024);                 // B*(MAXSEG+1)
  int*   seg_id     = (int*)(ws + 8192);                 // B*S
  int*   posSegOff  = (int*)(ws + 40960);                // B*(MAXSEG+1)
  int*   posSeg     = (int*)(ws + 49152);                // B*S
  int*   allowCnt   = (int*)(ws + 81920);                // B*256
  int*   firstAllow = (int*)(ws + 86016);                // B*256
  _Float16* segsum_h = (_Float16*)(ws + 90112);          // 1.5 MB
  _Float16* Wh       = (_Float16*)(ws + 1662976);        // 1.125 MB
  _Float16* Uh       = (_Float16*)(ws + 2842624);        // 1.5 MB
  float*    G        = (float*)(ws + 4415488);           // 1 MB

  k_scan<<<BB + 576, 256, 0, stream>>>(ind, clc, W, Wh, seg_id, seg_start,
                                       nseg, pos_cnt, allowCnt, firstAllow,
                                       posSegOff, posSeg, accum, counter);
  k_segsum<<<BB*MAXSEG, 192, 0, stream>>>(es, seg_start, nseg, segsum_h);
  k_gemmU<<<192, 256, 0, stream>>>(segsum_h, Wh, bias, Uh);
  k_gram<<<256, 256, 0, stream>>>(Uh, G);
  k_tail<<<256, 256, 0, stream>>>(G, seg_id, clc, nseg, pos_cnt, allowCnt,
                                  firstAllow, posSegOff, posSeg,
                                  accum, counter, out);
}